// Round 6
// baseline (909.544 us; speedup 1.0000x reference)
//
#include <hip/hip_runtime.h>
#include <hip/hip_bf16.h>
#include <hip/hip_cooperative_groups.h>
#include <math.h>

namespace cg = cooperative_groups;

#define N_ATOMS 4096
#define L_WORDS 65536
#define DD 10
#define HALO 11

// ===========================================================================
// MEGA cooperative kernel: whole network in one launch, 8 grid.sync()s.
// grid = 768 blocks x 256 thr = exactly 3 blocks/CU on 256 CUs.
// LDS 20 KB/block -> 60 KB/CU; launch_bounds(256,3) caps VGPR for 3/CU.
// ===========================================================================
#define MG_GRID 768
#define MG_BLOCK 256
#define MG_QC 512                  // cols per gnn unit
#define MG_NQ 8                    // column chunks
#define MG_RPB 16                  // rows per gnn unit
#define MG_NRG (N_ATOMS / MG_RPB)  // 256 row groups
#define MG_NGNN (MG_NQ * MG_NRG)   // 2048 gnn units
#define MG_NCONV 256               // conv units (256 rows each)
#define MG_NU (MG_NCONV + MG_NGNN) // 2304 = 3 * 768 (perfect balance)

struct MegaArgs {
    const int* fp; const float* A; const int* words;
    const float* emb_fp; const float* emb_w;
    const float* Wg; const float* bg; const float* Wc; const float* bc;
    const float* Wa; const float* ba; const float* Wo; const float* bo;
    const float* Wi; const float* bi;
    float* out;
    float* xs0; float* xs1; float* hsT0; float* hsT1;
    float* ta; float* tb; float* part; float* comp_part; float* att_part;
};

// ---- gnn unit: 16 rows x 512 cols partial of A@hs; hs chunk in LDS ----
__device__ __forceinline__ void mg_gnn_unit(
    int g, const float* __restrict__ A, const float* __restrict__ hsT_in,
    float* __restrict__ part, float* sh)
{
    const int tid = threadIdx.x, wave = tid >> 6, lane = tid & 63;
    const int q = g & (MG_NQ - 1), rg = g >> 3;
    const int qb4 = q * (MG_QC / 4);

    // stage hsT chunk [10][512] = 1280 float4, coalesced
    {
        const float4* src = (const float4*)hsT_in;
        float4* dst = (float4*)sh;
        #pragma unroll
        for (int k = 0; k < 5; ++k) {
            int idx = k * 256 + tid;
            int row = idx >> 7, col = idx & 127;
            dst[row * 128 + col] = src[(size_t)row * (N_ATOMS / 4) + qb4 + col];
        }
    }
    __syncthreads();

    const int r0 = rg * MG_RPB + wave * 4;
    const float4* Ar = (const float4*)(A + (size_t)r0 * N_ATOMS) + qb4;
    const float4* sh4 = (const float4*)sh;

    float acc[4][DD];
    #pragma unroll
    for (int r = 0; r < 4; ++r)
        #pragma unroll
        for (int d = 0; d < DD; ++d) acc[r][d] = 0.f;

    #pragma unroll
    for (int it = 0; it < 2; ++it) {
        const int cb = it * 64 + lane;
        float4 a0 = Ar[cb];
        float4 a1 = Ar[1024 + cb];      // +1 row = 4096 floats = 1024 f4
        float4 a2 = Ar[2048 + cb];
        float4 a3 = Ar[3072 + cb];
        #pragma unroll
        for (int d = 0; d < DD; ++d) {
            float4 h = sh4[d * 128 + cb];
            acc[0][d] += a0.x*h.x + a0.y*h.y + a0.z*h.z + a0.w*h.w;
            acc[1][d] += a1.x*h.x + a1.y*h.y + a1.z*h.z + a1.w*h.w;
            acc[2][d] += a2.x*h.x + a2.y*h.y + a2.z*h.z + a2.w*h.w;
            acc[3][d] += a3.x*h.x + a3.y*h.y + a3.z*h.z + a3.w*h.w;
        }
    }

    #pragma unroll
    for (int m = 32; m >= 1; m >>= 1) {
        #pragma unroll
        for (int r = 0; r < 4; ++r)
            #pragma unroll
            for (int d = 0; d < DD; ++d)
                acc[r][d] += __shfl_xor(acc[r][d], m, 64);
    }
    if (lane == 0) {
        #pragma unroll
        for (int r = 0; r < 4; ++r)
            #pragma unroll
            for (int d = 0; d < DD; ++d)
                part[((size_t)q * N_ATOMS + r0 + r) * DD + d] = acc[r][d];
    }
    __syncthreads();   // before next unit reuses sh
}

// ---- conv unit: 256 output rows of the 23x23 conv ----
__device__ __forceinline__ void mg_conv_unit(
    int c, const float* __restrict__ tin, const int* __restrict__ words,
    const float* __restrict__ emb_w, const float* __restrict__ w,
    const float* __restrict__ bptr, float* __restrict__ tout, float* sh)
{
    const int tid = threadIdx.x;
    const int l0 = c * 256;

    for (int idx = tid; idx < (256 + 2 * HALO) * DD; idx += 256) {
        int rr = idx / DD, d = idx - rr * DD;
        int gr = l0 - HALO + rr;
        float v = 0.f;
        if (gr >= 0 && gr < L_WORDS) {
            if (tin) v = tin[(size_t)gr * DD + d];
            else     v = emb_w[(size_t)words[gr] * DD + d];
        }
        sh[rr * 11 + d] = v;      // stride 11: conflict-free
    }
    __syncthreads();

    const float bias = *bptr;
    float acc[DD];
    #pragma unroll
    for (int d = 0; d < DD; ++d) acc[d] = bias;

    for (int i = 0; i < 23; ++i) {
        float row[DD];
        const float* sr = &sh[(tid + i) * 11];
        #pragma unroll
        for (int cc = 0; cc < DD; ++cc) row[cc] = sr[cc];
        #pragma unroll
        for (int d = 0; d < DD; ++d) {
            #pragma unroll
            for (int cc = 0; cc < DD; ++cc)
                acc[d] += row[cc] * w[i * 23 + (cc - d + 11)];
        }
    }
    const int l = l0 + tid;
    #pragma unroll
    for (int d = 0; d < DD; ++d)
        tout[(size_t)l * DD + d] = fmaxf(acc[d], 0.f);
    __syncthreads();   // before next unit reuses sh
}

__device__ __forceinline__ void mg_phaseA(
    int layer, const float* A, const float* hsT_in, float* part,
    const float* tin, const int* words, const float* emb_w,
    const float* Wc, const float* bc, float* tout, float* sh)
{
    for (int u = blockIdx.x; u < MG_NU; u += MG_GRID) {
        if (u < MG_NCONV)
            mg_conv_unit(u, tin, words, emb_w, Wc + 529 * layer, bc + layer,
                         tout, sh);
        else
            mg_gnn_unit(u - MG_NCONV, A, hsT_in, part, sh);
    }
}

// ---- combine: xs_out = xs_in + sum_q part; optional hsT_out / comp_part ----
__device__ __forceinline__ void mg_combine(
    const float* xs_in, const float* part, float* xs_out, float* hsT_out,
    const float* Wg, const float* bg, float* comp_part, float* sh)
{
    if (blockIdx.x < 16) {
        const int tid = threadIdx.x, wave = tid >> 6, lane = tid & 63;
        const int n = blockIdx.x * 256 + tid;
        float x[DD];
        #pragma unroll
        for (int d = 0; d < DD; ++d) {
            float v = xs_in[n * DD + d];
            #pragma unroll
            for (int q = 0; q < MG_NQ; ++q)
                v += part[((size_t)q * N_ATOMS + n) * DD + d];
            x[d] = v;
        }
        if (xs_out) {
            #pragma unroll
            for (int d = 0; d < DD; ++d) xs_out[n * DD + d] = x[d];
        }
        if (hsT_out) {
            #pragma unroll
            for (int d = 0; d < DD; ++d) {
                float v = bg[d];
                #pragma unroll
                for (int k = 0; k < DD; ++k) v += Wg[d * DD + k] * x[k];
                hsT_out[(size_t)d * N_ATOMS + n] = fmaxf(v, 0.f);
            }
        }
        if (comp_part) {
            #pragma unroll
            for (int m = 32; m >= 1; m >>= 1) {
                #pragma unroll
                for (int d = 0; d < DD; ++d) x[d] += __shfl_xor(x[d], m, 64);
            }
            if (lane == 0) {
                #pragma unroll
                for (int d = 0; d < DD; ++d) sh[wave * DD + d] = x[d];
            }
            __syncthreads();
            if (tid < DD)
                comp_part[blockIdx.x * DD + tid] =
                    sh[tid] + sh[DD + tid] + sh[2 * DD + tid] + sh[3 * DD + tid];
        }
    }
}

// ---- attention: blocks 0..255, 256 rows each -> att_part[256][10] ----
__device__ __forceinline__ void mg_att(
    const float* xs_p, const float* comp_part,
    const float* Wa, const float* ba, float* att_part, float* sh)
{
    if (blockIdx.x < 256) {
        const int tid = threadIdx.x, wave = tid >> 6, lane = tid & 63;
        if (tid < DD) {
            float c = 0.f;
            #pragma unroll
            for (int p = 0; p < 16; ++p) c += comp_part[p * DD + tid];
            sh[tid] = c * (1.f / N_ATOMS);
        }
        __syncthreads();
        float compv[DD];
        #pragma unroll
        for (int d = 0; d < DD; ++d) compv[d] = sh[d];

        float h[DD];
        #pragma unroll
        for (int d = 0; d < DD; ++d) {
            float v = ba[d];
            #pragma unroll
            for (int k = 0; k < DD; ++k) v += Wa[d * DD + k] * compv[k];
            h[d] = fmaxf(v, 0.f);
        }

        const int l = blockIdx.x * 256 + tid;
        float row[DD];
        #pragma unroll
        for (int d = 0; d < DD; ++d) row[d] = xs_p[(size_t)l * DD + d];

        float hp[DD], dotv = 0.f;
        #pragma unroll
        for (int d = 0; d < DD; ++d) {
            float v = ba[d];
            #pragma unroll
            for (int k = 0; k < DD; ++k) v += Wa[d * DD + k] * row[k];
            hp[d] = fmaxf(v, 0.f);
            dotv += h[d] * hp[d];
        }
        const float wgt = tanhf(dotv);

        float y[DD];
        #pragma unroll
        for (int d = 0; d < DD; ++d) y[d] = wgt * hp[d];
        #pragma unroll
        for (int m = 32; m >= 1; m >>= 1) {
            #pragma unroll
            for (int d = 0; d < DD; ++d) y[d] += __shfl_xor(y[d], m, 64);
        }
        __syncthreads();
        if (lane == 0) {
            #pragma unroll
            for (int d = 0; d < DD; ++d) sh[wave * DD + d] = y[d];
        }
        __syncthreads();
        if (tid < DD)
            att_part[blockIdx.x * DD + tid] =
                sh[tid] + sh[DD + tid] + sh[2 * DD + tid] + sh[3 * DD + tid];
    }
}

// ---- final: block 0 reduces att_part, builds cat, runs MLP ----
__device__ __forceinline__ void mg_fin(
    const float* att_part, const float* comp_part,
    const float* Wo, const float* bo, const float* Wi, const float* bi,
    float* out, float* sh)
{
    if (blockIdx.x == 0) {
        const int tid = threadIdx.x, wave = tid >> 6, lane = tid & 63;
        float v[DD];
        #pragma unroll
        for (int d = 0; d < DD; ++d) v[d] = att_part[tid * DD + d];
        #pragma unroll
        for (int m = 32; m >= 1; m >>= 1) {
            #pragma unroll
            for (int d = 0; d < DD; ++d) v[d] += __shfl_xor(v[d], m, 64);
        }
        if (lane == 0) {
            #pragma unroll
            for (int d = 0; d < DD; ++d) sh[32 + wave * DD + d] = v[d];
        }
        __syncthreads();
        if (tid < DD) {
            float c = 0.f;
            #pragma unroll
            for (int p = 0; p < 16; ++p) c += comp_part[p * DD + tid];
            sh[tid] = c * (1.f / N_ATOMS);
            float pr = sh[32 + tid] + sh[32 + DD + tid]
                     + sh[32 + 2 * DD + tid] + sh[32 + 3 * DD + tid];
            sh[DD + tid] = pr * (1.f / L_WORDS);
        }
        __syncthreads();
        for (int j = 0; j < 3; ++j) {
            float vv = 0.f;
            if (tid < 20) {
                vv = bo[j * 20 + tid];
                for (int k = 0; k < 20; ++k)
                    vv += Wo[j * 400 + tid * 20 + k] * sh[k];
            }
            __syncthreads();
            if (tid < 20) sh[tid] = fmaxf(vv, 0.f);
            __syncthreads();
        }
        if (tid < 2) {
            float vv = bi[tid];
            for (int k = 0; k < 20; ++k) vv += Wi[tid * 20 + k] * sh[k];
            out[tid] = vv;
        }
    }
}

__global__ __launch_bounds__(MG_BLOCK, 3) void mega(MegaArgs a)
{
    __shared__ float sh[DD * MG_QC];   // 20 KB
    cg::grid_group grid = cg::this_grid();
    const int tid = threadIdx.x;

    // embed: blocks 0..15, one atom/thread
    if (blockIdx.x < 16) {
        const int n = blockIdx.x * 256 + tid;
        float x[DD];
        const float* e = a.emb_fp + (size_t)a.fp[n] * DD;
        #pragma unroll
        for (int d = 0; d < DD; ++d) { x[d] = e[d]; a.xs0[n * DD + d] = x[d]; }
        #pragma unroll
        for (int d = 0; d < DD; ++d) {
            float v = a.bg[d];
            #pragma unroll
            for (int k = 0; k < DD; ++k) v += a.Wg[d * DD + k] * x[k];
            a.hsT0[(size_t)d * N_ATOMS + n] = fmaxf(v, 0.f);
        }
    }
    grid.sync();

    mg_phaseA(0, a.A, a.hsT0, a.part, nullptr, a.words, a.emb_w, a.Wc, a.bc,
              a.ta, sh);
    grid.sync();
    mg_combine(a.xs0, a.part, a.xs1, a.hsT1, a.Wg + 100, a.bg + 10, nullptr, sh);
    grid.sync();

    mg_phaseA(1, a.A, a.hsT1, a.part, a.ta, a.words, a.emb_w, a.Wc, a.bc,
              a.tb, sh);
    grid.sync();
    mg_combine(a.xs1, a.part, a.xs0, a.hsT0, a.Wg + 200, a.bg + 20, nullptr, sh);
    grid.sync();

    mg_phaseA(2, a.A, a.hsT0, a.part, a.tb, a.words, a.emb_w, a.Wc, a.bc,
              a.ta, sh);
    grid.sync();
    mg_combine(a.xs0, a.part, nullptr, nullptr, nullptr, nullptr,
               a.comp_part, sh);
    grid.sync();

    mg_att(a.ta, a.comp_part, a.Wa, a.ba, a.att_part, sh);
    grid.sync();
    mg_fin(a.att_part, a.comp_part, a.Wo, a.bo, a.Wi, a.bi, a.out, sh);
}

// ===========================================================================
// FALLBACK path (round-5 kernels) — used if cooperative launch fails.
// ===========================================================================
#define GP_RPW 4
#define GP_ROWS_BLK 16
#define GP_QCOLS 1024
#define CONV_BLOCKS 256
#define CONV_BLOCK 256

__global__ __launch_bounds__(256) void gnn_embed(
    const int* __restrict__ fp, const float* __restrict__ embed_fp,
    const float* __restrict__ Wg0, const float* __restrict__ bg0,
    float* __restrict__ xs0, float* __restrict__ hsT0)
{
    int n = blockIdx.x * blockDim.x + threadIdx.x;
    if (n >= N_ATOMS) return;
    float x[DD];
    const float* e = embed_fp + (size_t)fp[n] * DD;
    #pragma unroll
    for (int d = 0; d < DD; ++d) { x[d] = e[d]; xs0[n * DD + d] = x[d]; }
    #pragma unroll
    for (int d = 0; d < DD; ++d) {
        float v = bg0[d];
        #pragma unroll
        for (int k = 0; k < DD; ++k) v += Wg0[d * DD + k] * x[k];
        hsT0[d * N_ATOMS + n] = fmaxf(v, 0.f);
    }
}

__global__ __launch_bounds__(256, 4) void fused_layer(
    const float* __restrict__ A, const float* __restrict__ hsT_in,
    float* __restrict__ part,
    const float* __restrict__ tin, const int* __restrict__ words,
    const float* __restrict__ embed_word, const float* __restrict__ w,
    const float* __restrict__ bptr, float* __restrict__ tout)
{
    __shared__ float sh[DD * GP_QCOLS];
    const int tid = threadIdx.x;

    if (blockIdx.x < CONV_BLOCKS) {
        float* s = sh;
        const int l0 = blockIdx.x * CONV_BLOCK;
        for (int idx = tid; idx < (CONV_BLOCK + 2 * HALO) * DD; idx += CONV_BLOCK) {
            int rr = idx / DD, d = idx - rr * DD;
            int gr = l0 - HALO + rr;
            float v = 0.f;
            if (gr >= 0 && gr < L_WORDS) {
                if (tin) v = tin[(size_t)gr * DD + d];
                else     v = embed_word[(size_t)words[gr] * DD + d];
            }
            s[rr * 11 + d] = v;
        }
        __syncthreads();
        const float bias = *bptr;
        float acc[DD];
        #pragma unroll
        for (int d = 0; d < DD; ++d) acc[d] = bias;
        for (int i = 0; i < 23; ++i) {
            float row[DD];
            const float* sr = &s[(tid + i) * 11];
            #pragma unroll
            for (int c = 0; c < DD; ++c) row[c] = sr[c];
            #pragma unroll
            for (int d = 0; d < DD; ++d) {
                #pragma unroll
                for (int c = 0; c < DD; ++c)
                    acc[d] += row[c] * w[i * 23 + (c - d + 11)];
            }
        }
        const int l = l0 + tid;
        #pragma unroll
        for (int d = 0; d < DD; ++d)
            tout[(size_t)l * DD + d] = fmaxf(acc[d], 0.f);
    } else {
        const int b = blockIdx.x - CONV_BLOCKS;
        const int wave = tid >> 6, lane = tid & 63;
        const int q = b & 3, rg = b >> 2;
        const int qbase = q * GP_QCOLS;
        {
            const float4* src = (const float4*)(hsT_in + qbase);
            float4* dst = (float4*)sh;
            #pragma unroll
            for (int k = 0; k < DD; ++k)
                dst[k * 256 + tid] = src[k * (N_ATOMS / 4) + tid];
        }
        __syncthreads();
        const int r0 = rg * GP_ROWS_BLK + wave * GP_RPW;
        const float4* Ar[GP_RPW];
        #pragma unroll
        for (int r = 0; r < GP_RPW; ++r)
            Ar[r] = (const float4*)(A + (size_t)(r0 + r) * N_ATOMS + qbase);
        const float4* sh4 = (const float4*)sh;
        float acc[GP_RPW][DD];
        #pragma unroll
        for (int r = 0; r < GP_RPW; ++r)
            #pragma unroll
            for (int d = 0; d < DD; ++d) acc[r][d] = 0.f;
        #pragma unroll
        for (int it = 0; it < GP_QCOLS / 256; ++it) {
            const int cb = it * 64 + lane;
            float4 av[GP_RPW];
            #pragma unroll
            for (int r = 0; r < GP_RPW; ++r) av[r] = Ar[r][cb];
            #pragma unroll
            for (int d = 0; d < DD; ++d) {
                float4 h = sh4[d * 256 + cb];
                #pragma unroll
                for (int r = 0; r < GP_RPW; ++r) {
                    acc[r][d] += av[r].x * h.x;
                    acc[r][d] += av[r].y * h.y;
                    acc[r][d] += av[r].z * h.z;
                    acc[r][d] += av[r].w * h.w;
                }
            }
        }
        #pragma unroll
        for (int m = 32; m >= 1; m >>= 1) {
            #pragma unroll
            for (int r = 0; r < GP_RPW; ++r)
                #pragma unroll
                for (int d = 0; d < DD; ++d)
                    acc[r][d] += __shfl_xor(acc[r][d], m, 64);
        }
        if (lane == 0) {
            #pragma unroll
            for (int r = 0; r < GP_RPW; ++r)
                #pragma unroll
                for (int d = 0; d < DD; ++d)
                    part[((size_t)q * N_ATOMS + r0 + r) * DD + d] = acc[r][d];
        }
    }
}

__global__ __launch_bounds__(256) void gnn_combine(
    const float* __restrict__ xs_in, const float* __restrict__ part,
    float* __restrict__ xs_out, float* __restrict__ hsT_out,
    const float* __restrict__ Wg, const float* __restrict__ bg,
    float* __restrict__ comp_part)
{
    const int tid = threadIdx.x, wave = tid >> 6, lane = tid & 63;
    const int n = blockIdx.x * 256 + tid;
    float x[DD];
    #pragma unroll
    for (int d = 0; d < DD; ++d) {
        float v = xs_in[n * DD + d];
        #pragma unroll
        for (int q = 0; q < 4; ++q)
            v += part[((size_t)q * N_ATOMS + n) * DD + d];
        x[d] = v;
        xs_out[n * DD + d] = v;
    }
    if (hsT_out) {
        #pragma unroll
        for (int d = 0; d < DD; ++d) {
            float v = bg[d];
            #pragma unroll
            for (int k = 0; k < DD; ++k) v += Wg[d * DD + k] * x[k];
            hsT_out[(size_t)d * N_ATOMS + n] = fmaxf(v, 0.f);
        }
    }
    if (comp_part) {
        #pragma unroll
        for (int m = 32; m >= 1; m >>= 1) {
            #pragma unroll
            for (int d = 0; d < DD; ++d) x[d] += __shfl_xor(x[d], m, 64);
        }
        __shared__ float s[4][DD];
        if (lane == 0) {
            #pragma unroll
            for (int d = 0; d < DD; ++d) s[wave][d] = x[d];
        }
        __syncthreads();
        if (tid < DD)
            comp_part[blockIdx.x * DD + tid] =
                s[0][tid] + s[1][tid] + s[2][tid] + s[3][tid];
    }
}

__global__ __launch_bounds__(256) void reduce_comp(
    const float* __restrict__ part, int npart, float* __restrict__ comp)
{
    const int tid = threadIdx.x, wave = tid >> 6, lane = tid & 63;
    float v[DD];
    #pragma unroll
    for (int d = 0; d < DD; ++d) v[d] = 0.f;
    for (int p = tid; p < npart; p += 256) {
        #pragma unroll
        for (int d = 0; d < DD; ++d) v[d] += part[p * DD + d];
    }
    #pragma unroll
    for (int off = 32; off >= 1; off >>= 1) {
        #pragma unroll
        for (int d = 0; d < DD; ++d) v[d] += __shfl_down(v[d], off, 64);
    }
    __shared__ float s[4][DD];
    if (lane == 0) {
        #pragma unroll
        for (int d = 0; d < DD; ++d) s[wave][d] = v[d];
    }
    __syncthreads();
    if (tid < DD)
        comp[tid] = (s[0][tid] + s[1][tid] + s[2][tid] + s[3][tid]) * (1.f / N_ATOMS);
}

__global__ __launch_bounds__(1024) void attention_pool(
    const float* __restrict__ xs_p, const float* __restrict__ comp,
    const float* __restrict__ Wa, const float* __restrict__ ba,
    float* __restrict__ att_part)
{
    const int tid = threadIdx.x, wave = tid >> 6, lane = tid & 63;
    const int l = blockIdx.x * 1024 + tid;
    float h[DD];
    #pragma unroll
    for (int d = 0; d < DD; ++d) {
        float v = ba[d];
        #pragma unroll
        for (int k = 0; k < DD; ++k) v += Wa[d * DD + k] * comp[k];
        h[d] = fmaxf(v, 0.f);
    }
    float row[DD];
    #pragma unroll
    for (int d = 0; d < DD; ++d) row[d] = xs_p[(size_t)l * DD + d];
    float hp[DD], dotv = 0.f;
    #pragma unroll
    for (int d = 0; d < DD; ++d) {
        float v = ba[d];
        #pragma unroll
        for (int k = 0; k < DD; ++k) v += Wa[d * DD + k] * row[k];
        hp[d] = fmaxf(v, 0.f);
        dotv += h[d] * hp[d];
    }
    const float wgt = tanhf(dotv);
    float y[DD];
    #pragma unroll
    for (int d = 0; d < DD; ++d) y[d] = wgt * hp[d];
    #pragma unroll
    for (int off = 32; off >= 1; off >>= 1) {
        #pragma unroll
        for (int d = 0; d < DD; ++d) y[d] += __shfl_down(y[d], off, 64);
    }
    __shared__ float s[16][DD];
    if (lane == 0) {
        #pragma unroll
        for (int d = 0; d < DD; ++d) s[wave][d] = y[d];
    }
    __syncthreads();
    if (tid < DD) {
        float v = 0.f;
        #pragma unroll
        for (int wv = 0; wv < 16; ++wv) v += s[wv][tid];
        att_part[blockIdx.x * DD + tid] = v;
    }
}

__global__ __launch_bounds__(64) void final_mlp(
    const float* __restrict__ comp, const float* __restrict__ att_part,
    const float* __restrict__ Wo, const float* __restrict__ bo,
    const float* __restrict__ Wi, const float* __restrict__ bi,
    float* __restrict__ out)
{
    const int t = threadIdx.x;
    float a[DD];
    #pragma unroll
    for (int d = 0; d < DD; ++d) a[d] = att_part[t * DD + d];
    #pragma unroll
    for (int off = 32; off >= 1; off >>= 1) {
        #pragma unroll
        for (int d = 0; d < DD; ++d) a[d] += __shfl_down(a[d], off, 64);
    }
    __shared__ float cat[20];
    if (t < DD) cat[t] = comp[t];
    if (t == 0) {
        #pragma unroll
        for (int d = 0; d < DD; ++d) cat[DD + d] = a[d] * (1.f / L_WORDS);
    }
    __syncthreads();
    for (int j = 0; j < 3; ++j) {
        float v = 0.f;
        if (t < 20) {
            v = bo[j * 20 + t];
            for (int k = 0; k < 20; ++k) v += Wo[j * 400 + t * 20 + k] * cat[k];
        }
        __syncthreads();
        if (t < 20) cat[t] = fmaxf(v, 0.f);
        __syncthreads();
    }
    if (t < 2) {
        float v = bi[t];
        for (int k = 0; k < 20; ++k) v += Wi[t * 20 + k] * cat[k];
        out[t] = v;
    }
}

// ---------------------------------------------------------------------------
extern "C" void kernel_launch(void* const* d_in, const int* in_sizes, int n_in,
                              void* d_out, int out_size, void* d_ws, size_t ws_size,
                              hipStream_t stream)
{
    const int*   fp     = (const int*)d_in[0];
    const float* A      = (const float*)d_in[1];
    const int*   words  = (const int*)d_in[2];
    const float* emb_fp = (const float*)d_in[3];
    const float* emb_w  = (const float*)d_in[4];
    const float* Wg     = (const float*)d_in[5];
    const float* bg     = (const float*)d_in[6];
    const float* Wc     = (const float*)d_in[7];
    const float* bc     = (const float*)d_in[8];
    const float* Wa     = (const float*)d_in[9];
    const float* ba     = (const float*)d_in[10];
    const float* Wo     = (const float*)d_in[11];
    const float* bo     = (const float*)d_in[12];
    const float* Wi     = (const float*)d_in[13];
    const float* bi     = (const float*)d_in[14];
    float* out = (float*)d_out;
    float* ws  = (float*)d_ws;

    float* xs0  = ws;                        // 40960
    float* xs1  = ws + 40960;                // 40960
    float* hsT0 = ws + 81920;                // 40960
    float* hsT1 = ws + 122880;               // 40960
    float* ta   = ws + 163840;               // 655360
    float* tb   = ws + 819200;               // 655360
    float* part = ws + 1474560;              // 327680 (mega: 8q; fallback: 4q)
    float* comp_part = ws + 1802240;         // 160
    float* att_part  = ws + 1802496;         // 2560
    float* comp      = ws + 1805056;         // 16 (fallback)

    MegaArgs ma = { fp, A, words, emb_fp, emb_w, Wg, bg, Wc, bc,
                    Wa, ba, Wo, bo, Wi, bi, out,
                    xs0, xs1, hsT0, hsT1, ta, tb, part, comp_part, att_part };
    void* kp[1] = { &ma };
    hipError_t err = hipLaunchCooperativeKernel(
        (void*)mega, dim3(MG_GRID), dim3(MG_BLOCK), kp, 0, stream);

    if (err != hipSuccess) {
        (void)hipGetLastError();   // clear sticky error, use fallback path
        const int fused_grid = CONV_BLOCKS + (N_ATOMS / GP_ROWS_BLK) * 4;
        gnn_embed<<<N_ATOMS / 256, 256, 0, stream>>>(fp, emb_fp, Wg, bg, xs0, hsT0);
        fused_layer<<<fused_grid, 256, 0, stream>>>(
            A, hsT0, part, nullptr, words, emb_w, Wc, bc, ta);
        gnn_combine<<<N_ATOMS / 256, 256, 0, stream>>>(
            xs0, part, xs1, hsT1, Wg + 100, bg + 10, nullptr);
        fused_layer<<<fused_grid, 256, 0, stream>>>(
            A, hsT1, part, ta, nullptr, nullptr, Wc + 529, bc + 1, tb);
        gnn_combine<<<N_ATOMS / 256, 256, 0, stream>>>(
            xs1, part, xs0, hsT0, Wg + 200, bg + 20, nullptr);
        fused_layer<<<fused_grid, 256, 0, stream>>>(
            A, hsT0, part, tb, nullptr, nullptr, Wc + 1058, bc + 2, ta);
        gnn_combine<<<N_ATOMS / 256, 256, 0, stream>>>(
            xs0, part, xs1, nullptr, nullptr, nullptr, comp_part);
        reduce_comp<<<1, 256, 0, stream>>>(comp_part, 16, comp);
        attention_pool<<<L_WORDS / 1024, 1024, 0, stream>>>(ta, comp, Wa, ba, att_part);
        final_mlp<<<1, 64, 0, stream>>>(comp, att_part, Wo, bo, Wi, bi, out);
    }
}

// Round 7
// 769.856 us; speedup vs baseline: 1.1814x; 1.1814x over previous
//
#include <hip/hip_runtime.h>
#include <hip/hip_bf16.h>
#include <math.h>

#define N_ATOMS 4096
#define L_WORDS 65536
#define DD 10
#define HALO 11

#define GP_RPW 4
#define GP_ROWS_BLK 16
#define GP_QCOLS 1024
#define CONV_BLOCKS 256
#define CONV_BLOCK 256
#define N_RG (N_ATOMS / GP_ROWS_BLK)     // 256 row groups

// ---------------------------------------------------------------------------
// K1: embedding gather + hsT0; block 0 also zeroes the epilogue counters.
// ---------------------------------------------------------------------------
__global__ __launch_bounds__(256) void gnn_embed(
    const int* __restrict__ fp, const float* __restrict__ embed_fp,
    const float* __restrict__ Wg0, const float* __restrict__ bg0,
    float* __restrict__ xs0, float* __restrict__ hsT0,
    int* __restrict__ cnts)              // [3*256 + 2] ints
{
    const int tid = threadIdx.x;
    if (blockIdx.x == 0) {
        for (int i = tid; i < 3 * N_RG + 2; i += 256) cnts[i] = 0;
    }
    int n = blockIdx.x * blockDim.x + tid;
    if (n >= N_ATOMS) return;
    float x[DD];
    const float* e = embed_fp + (size_t)fp[n] * DD;
    #pragma unroll
    for (int d = 0; d < DD; ++d) { x[d] = e[d]; xs0[n * DD + d] = x[d]; }
    #pragma unroll
    for (int d = 0; d < DD; ++d) {
        float v = bg0[d];
        #pragma unroll
        for (int k = 0; k < DD; ++k) v += Wg0[d * DD + k] * x[k];
        hsT0[d * N_ATOMS + n] = fmaxf(v, 0.f);
    }
}

// ---------------------------------------------------------------------------
// K2: fused_layer — role-split grid + counter-elected combine epilogue.
//  blocks [0,256):    CNN layer (VALU-bound)
//  blocks [256,1280): GNN partial A@hs over a column quarter; the LAST of the
//                     4 quarter-blocks per 16-row group (device-scope
//                     atomicAdd on cnt[rg]) combines partials -> xs_out,
//                     next-layer hsT_out, or compound partials. The global-
//                     last row group (comp_cnt) reduces comp_part -> comp.
// No spinning anywhere: no deadlock risk; kernel-boundary gives next layer
// its ordering.
// ---------------------------------------------------------------------------
__global__ __launch_bounds__(256, 4) void fused_layer(
    const float* __restrict__ A, const float* __restrict__ hsT_in,
    float* __restrict__ part,
    const float* __restrict__ xs_in, float* __restrict__ xs_out,
    float* __restrict__ hsT_out,         // may be null
    const float* __restrict__ Wg, const float* __restrict__ bg,
    float* __restrict__ comp_part,       // may be null; [256][DD]
    float* __restrict__ comp,            // may be null; [DD]
    int* __restrict__ cnt,               // [256] per-row-group counters
    int* __restrict__ comp_cnt,          // single counter
    const float* __restrict__ tin, const int* __restrict__ words,
    const float* __restrict__ embed_word, const float* __restrict__ w,
    const float* __restrict__ bptr, float* __restrict__ tout)
{
    __shared__ float sh[DD * GP_QCOLS];  // 40 KB
    __shared__ int s_last, s_last2;
    const int tid = threadIdx.x;

    if (blockIdx.x < CONV_BLOCKS) {
        // ================= CONV ROLE =================
        float* s = sh;
        const int l0 = blockIdx.x * CONV_BLOCK;
        for (int idx = tid; idx < (CONV_BLOCK + 2 * HALO) * DD; idx += CONV_BLOCK) {
            int rr = idx / DD, d = idx - rr * DD;
            int gr = l0 - HALO + rr;
            float v = 0.f;
            if (gr >= 0 && gr < L_WORDS) {
                if (tin) v = tin[(size_t)gr * DD + d];
                else     v = embed_word[(size_t)words[gr] * DD + d];
            }
            s[rr * 11 + d] = v;          // stride 11: conflict-free
        }
        __syncthreads();

        const float bias = *bptr;
        float acc[DD];
        #pragma unroll
        for (int d = 0; d < DD; ++d) acc[d] = bias;
        for (int i = 0; i < 23; ++i) {
            float row[DD];
            const float* sr = &s[(tid + i) * 11];
            #pragma unroll
            for (int c = 0; c < DD; ++c) row[c] = sr[c];
            #pragma unroll
            for (int d = 0; d < DD; ++d) {
                #pragma unroll
                for (int c = 0; c < DD; ++c)
                    acc[d] += row[c] * w[i * 23 + (c - d + 11)];
            }
        }
        const int l = l0 + tid;
        #pragma unroll
        for (int d = 0; d < DD; ++d)
            tout[(size_t)l * DD + d] = fmaxf(acc[d], 0.f);
    } else {
        // ================= GNN ROLE =================
        const int b = blockIdx.x - CONV_BLOCKS;
        const int wave = tid >> 6, lane = tid & 63;
        const int q = b & 3, rg = b >> 2;
        const int qbase = q * GP_QCOLS;

        {   // stage hsT quarter [10][1024], coalesced
            const float4* src = (const float4*)(hsT_in + qbase);
            float4* dst = (float4*)sh;
            #pragma unroll
            for (int k = 0; k < DD; ++k)
                dst[k * 256 + tid] = src[k * (N_ATOMS / 4) + tid];
        }
        __syncthreads();

        const int r0 = rg * GP_ROWS_BLK + wave * GP_RPW;
        const float4* Ar[GP_RPW];
        #pragma unroll
        for (int r = 0; r < GP_RPW; ++r)
            Ar[r] = (const float4*)(A + (size_t)(r0 + r) * N_ATOMS + qbase);
        const float4* sh4 = (const float4*)sh;

        float acc[GP_RPW][DD];
        #pragma unroll
        for (int r = 0; r < GP_RPW; ++r)
            #pragma unroll
            for (int d = 0; d < DD; ++d) acc[r][d] = 0.f;

        // 4 iterations fully unrolled: 16 independent A loads in flight
        #pragma unroll
        for (int it = 0; it < GP_QCOLS / 256; ++it) {
            const int cb = it * 64 + lane;
            float4 av[GP_RPW];
            #pragma unroll
            for (int r = 0; r < GP_RPW; ++r) av[r] = Ar[r][cb];
            #pragma unroll
            for (int d = 0; d < DD; ++d) {
                float4 h = sh4[d * 256 + cb];
                #pragma unroll
                for (int r = 0; r < GP_RPW; ++r) {
                    acc[r][d] += av[r].x * h.x;
                    acc[r][d] += av[r].y * h.y;
                    acc[r][d] += av[r].z * h.z;
                    acc[r][d] += av[r].w * h.w;
                }
            }
        }

        #pragma unroll
        for (int m = 32; m >= 1; m >>= 1) {
            #pragma unroll
            for (int r = 0; r < GP_RPW; ++r)
                #pragma unroll
                for (int d = 0; d < DD; ++d)
                    acc[r][d] += __shfl_xor(acc[r][d], m, 64);
        }
        if (lane == 0) {
            #pragma unroll
            for (int r = 0; r < GP_RPW; ++r)
                #pragma unroll
                for (int d = 0; d < DD; ++d)
                    part[((size_t)q * N_ATOMS + r0 + r) * DD + d] = acc[r][d];
            __threadfence();   // writer-side release
        }
        __syncthreads();
        if (tid == 0) s_last = (atomicAdd(&cnt[rg], 1) == 3);
        __syncthreads();

        if (s_last) {
            // ---- combine epilogue: this block is last of the 4 quarters ----
            __threadfence();   // reader-side acquire
            if (tid < GP_ROWS_BLK * DD) {
                const int row = tid / DD, d = tid - row * DD;
                const int n = rg * GP_ROWS_BLK + row;
                float v = xs_in[n * DD + d];
                #pragma unroll
                for (int qq = 0; qq < 4; ++qq)
                    v += part[((size_t)qq * N_ATOMS + n) * DD + d];
                if (xs_out) xs_out[n * DD + d] = v;
                sh[row * DD + d] = v;    // xnew[16][10] in LDS (staging done)
            }
            __syncthreads();
            if (hsT_out && tid < DD * GP_ROWS_BLK) {
                const int d = tid >> 4, n0 = tid & 15;   // d<10, n0<16
                float v = bg[d];
                #pragma unroll
                for (int k = 0; k < DD; ++k) v += Wg[d * DD + k] * sh[n0 * DD + k];
                hsT_out[(size_t)d * N_ATOMS + rg * GP_ROWS_BLK + n0] = fmaxf(v, 0.f);
            }
            if (comp_part) {
                if (tid < DD) {
                    float s = 0.f;
                    #pragma unroll
                    for (int row = 0; row < GP_ROWS_BLK; ++row) s += sh[row * DD + tid];
                    comp_part[rg * DD + tid] = s;
                }
                __threadfence();
                __syncthreads();
                if (tid == 0) s_last2 = (atomicAdd(comp_cnt, 1) == N_RG - 1);
                __syncthreads();
                if (s_last2) {
                    __threadfence();
                    if (tid < DD) {
                        float s = 0.f;
                        for (int p = 0; p < N_RG; ++p) s += comp_part[p * DD + tid];
                        comp[tid] = s * (1.f / N_ATOMS);
                    }
                }
            }
        }
    }
}

// ---------------------------------------------------------------------------
// K3: attention pooling; last block (att_cnt) reduces partials + runs the
// fusion MLP -> out[2].
// ---------------------------------------------------------------------------
__global__ __launch_bounds__(1024) void attention_fin(
    const float* __restrict__ xs_p, const float* __restrict__ comp,
    const float* __restrict__ Wa, const float* __restrict__ ba,
    float* __restrict__ att_part, int* __restrict__ att_cnt,
    const float* __restrict__ Wo, const float* __restrict__ bo,
    const float* __restrict__ Wi, const float* __restrict__ bi,
    float* __restrict__ out)
{
    __shared__ float s[16][DD];
    __shared__ float cat[32];
    __shared__ int s_last;
    const int tid = threadIdx.x, wave = tid >> 6, lane = tid & 63;
    const int l = blockIdx.x * 1024 + tid;

    float h[DD];
    #pragma unroll
    for (int d = 0; d < DD; ++d) {
        float v = ba[d];
        #pragma unroll
        for (int k = 0; k < DD; ++k) v += Wa[d * DD + k] * comp[k];
        h[d] = fmaxf(v, 0.f);
    }

    float row[DD];
    #pragma unroll
    for (int d = 0; d < DD; ++d) row[d] = xs_p[(size_t)l * DD + d];

    float hp[DD], dotv = 0.f;
    #pragma unroll
    for (int d = 0; d < DD; ++d) {
        float v = ba[d];
        #pragma unroll
        for (int k = 0; k < DD; ++k) v += Wa[d * DD + k] * row[k];
        hp[d] = fmaxf(v, 0.f);
        dotv += h[d] * hp[d];
    }
    const float wgt = tanhf(dotv);

    float y[DD];
    #pragma unroll
    for (int d = 0; d < DD; ++d) y[d] = wgt * hp[d];
    #pragma unroll
    for (int m = 32; m >= 1; m >>= 1) {
        #pragma unroll
        for (int d = 0; d < DD; ++d) y[d] += __shfl_xor(y[d], m, 64);
    }
    if (lane == 0) {
        #pragma unroll
        for (int d = 0; d < DD; ++d) s[wave][d] = y[d];
    }
    __syncthreads();
    if (tid < DD) {
        float v = 0.f;
        #pragma unroll
        for (int wv = 0; wv < 16; ++wv) v += s[wv][tid];
        att_part[blockIdx.x * DD + tid] = v;
    }
    __threadfence();
    __syncthreads();
    if (tid == 0) s_last = (atomicAdd(att_cnt, 1) == (L_WORDS / 1024) - 1);
    __syncthreads();

    if (s_last) {
        __threadfence();
        if (tid < 64) {
            float a[DD];
            #pragma unroll
            for (int d = 0; d < DD; ++d) a[d] = att_part[tid * DD + d];
            #pragma unroll
            for (int m = 32; m >= 1; m >>= 1) {
                #pragma unroll
                for (int d = 0; d < DD; ++d) a[d] += __shfl_xor(a[d], m, 64);
            }
            if (tid == 0) {
                #pragma unroll
                for (int d = 0; d < DD; ++d)
                    cat[DD + d] = a[d] * (1.f / L_WORDS);
            }
        }
        if (tid < DD) cat[tid] = comp[tid];
        __syncthreads();
        for (int j = 0; j < 3; ++j) {
            float v = 0.f;
            if (tid < 20) {
                v = bo[j * 20 + tid];
                for (int k = 0; k < 20; ++k) v += Wo[j * 400 + tid * 20 + k] * cat[k];
            }
            __syncthreads();
            if (tid < 20) cat[tid] = fmaxf(v, 0.f);
            __syncthreads();
        }
        if (tid < 2) {
            float v = bi[tid];
            for (int k = 0; k < 20; ++k) v += Wi[tid * 20 + k] * cat[k];
            out[tid] = v;
        }
    }
}

// ---------------------------------------------------------------------------
extern "C" void kernel_launch(void* const* d_in, const int* in_sizes, int n_in,
                              void* d_out, int out_size, void* d_ws, size_t ws_size,
                              hipStream_t stream)
{
    const int*   fp     = (const int*)d_in[0];
    const float* A      = (const float*)d_in[1];
    const int*   words  = (const int*)d_in[2];
    const float* emb_fp = (const float*)d_in[3];
    const float* emb_w  = (const float*)d_in[4];
    const float* Wg     = (const float*)d_in[5];   // [3][10][10]
    const float* bg     = (const float*)d_in[6];   // [3][10]
    const float* Wc     = (const float*)d_in[7];   // [3][529]
    const float* bc     = (const float*)d_in[8];   // [3]
    const float* Wa     = (const float*)d_in[9];   // [10][10]
    const float* ba     = (const float*)d_in[10];  // [10]
    const float* Wo     = (const float*)d_in[11];  // [3][20][20]
    const float* bo     = (const float*)d_in[12];  // [3][20]
    const float* Wi     = (const float*)d_in[13];  // [2][20]
    const float* bi     = (const float*)d_in[14];  // [2]
    float* out = (float*)d_out;
    float* ws  = (float*)d_ws;

    float* xs0  = ws;                        // 40960
    float* xs1  = ws + 40960;                // 40960
    float* hsT0 = ws + 81920;                // 40960
    float* hsT1 = ws + 122880;               // 40960
    float* ta   = ws + 163840;               // 655360
    float* tb   = ws + 819200;               // 655360
    float* part = ws + 1474560;              // 163840 (4 x 4096 x 10)
    float* comp_part = ws + 1638400;         // 2560  (256 x 10)
    float* att_part  = ws + 1640960;         // 640   (64 x 10)
    float* comp      = ws + 1641600;         // 16
    int*   cnts      = (int*)(ws + 1641616); // 770 ints
    int*   comp_cnt  = cnts + 3 * N_RG;
    int*   att_cnt   = comp_cnt + 1;

    const int fused_grid = CONV_BLOCKS + N_RG * 4;   // 1280

    // L0..L2: GNN layer i fused with CNN layer i; combine via counter-elected
    // epilogue inside the same launch.
    gnn_embed<<<N_ATOMS / 256, 256, 0, stream>>>(
        fp, emb_fp, Wg, bg, xs0, hsT0, cnts);

    fused_layer<<<fused_grid, 256, 0, stream>>>(
        A, hsT0, part, xs0, xs1, hsT1, Wg + 100, bg + 10,
        nullptr, nullptr, cnts + 0 * N_RG, comp_cnt,
        nullptr, words, emb_w, Wc, bc, ta);

    fused_layer<<<fused_grid, 256, 0, stream>>>(
        A, hsT1, part, xs1, xs0, hsT0, Wg + 200, bg + 20,
        nullptr, nullptr, cnts + 1 * N_RG, comp_cnt,
        ta, nullptr, nullptr, Wc + 529, bc + 1, tb);

    fused_layer<<<fused_grid, 256, 0, stream>>>(
        A, hsT0, part, xs0, nullptr, nullptr, nullptr, nullptr,
        comp_part, comp, cnts + 2 * N_RG, comp_cnt,
        tb, nullptr, nullptr, Wc + 1058, bc + 2, ta);

    attention_fin<<<L_WORDS / 1024, 1024, 0, stream>>>(
        ta, comp, Wa, ba, att_part, att_cnt, Wo, bo, Wi, bi, out);
}

// Round 8
// 210.835 us; speedup vs baseline: 4.3140x; 3.6515x over previous
//
#include <hip/hip_runtime.h>
#include <hip/hip_bf16.h>
#include <math.h>

#define N_ATOMS 4096
#define L_WORDS 65536
#define DD 10
#define HALO 11

#define CONV_BLOCKS 256
#define CONV_BLOCK 256
#define GNN_BLOCKS 512            // 128 row-groups x 4 column quarters
#define RPW 8                     // rows per wave
#define RPB 32                    // rows per block (4 waves)
#define QCOLS 1024                // columns per quarter

// ---------------------------------------------------------------------------
// K1: embedding gather -> xs0 only (hs is never materialized anywhere).
// ---------------------------------------------------------------------------
__global__ __launch_bounds__(256) void gnn_embed(
    const int* __restrict__ fp, const float* __restrict__ embed_fp,
    float* __restrict__ xs0)
{
    int n = blockIdx.x * blockDim.x + threadIdx.x;
    if (n >= N_ATOMS) return;
    const float* e = embed_fp + (size_t)fp[n] * DD;
    #pragma unroll
    for (int d = 0; d < DD; ++d) xs0[n * DD + d] = e[d];
}

// ---------------------------------------------------------------------------
// K2: fused_layer — role-split grid, NO atomics / NO fences (kernel-boundary
// ordering only; round-7 showed __threadfence costs ~100s of µs total).
//  blocks [0,256):   CNN layer (VALU-bound, hidden under GNN memory waits)
//  blocks [256,768): GNN partial A@hs over a 1024-column quarter.
//    Staging recomputes hs on the fly: x = xs0 + sum_q part0[+part1],
//    hs = relu(Wg@x+bg) -> LDS transposed [10][1024]. Redundant (128 blocks
//    share a quarter) but all L2-hit: ~100-200 MB/layer ≈ 3-6 µs aggregate,
//    cheaper than the combine launches it replaces.
//  Hot loop: 8 rows/wave, only A on the vmcnt queue, hs via ds_read_b128.
// ---------------------------------------------------------------------------
__global__ __launch_bounds__(256, 2) void fused_layer(
    const float* __restrict__ A,
    const float* __restrict__ xs0,
    const float* __restrict__ p0,        // part of layer 0 (null in L0)
    const float* __restrict__ p1,        // part of layer 1 (null in L0/L1)
    float* __restrict__ part,            // this layer's output [4][4096][10]
    const float* __restrict__ Wg, const float* __restrict__ bg,
    const float* __restrict__ tin, const int* __restrict__ words,
    const float* __restrict__ embed_word, const float* __restrict__ w,
    const float* __restrict__ bptr, float* __restrict__ tout)
{
    __shared__ float sh[DD * QCOLS];     // 40 KB exactly
    const int tid = threadIdx.x;

    if (blockIdx.x < CONV_BLOCKS) {
        // ================= CONV ROLE =================
        float* s = sh;                   // (256+22)*11 floats, stride 11
        const int l0 = blockIdx.x * CONV_BLOCK;
        for (int idx = tid; idx < (CONV_BLOCK + 2 * HALO) * DD; idx += CONV_BLOCK) {
            int rr = idx / DD, d = idx - rr * DD;
            int gr = l0 - HALO + rr;
            float v = 0.f;
            if (gr >= 0 && gr < L_WORDS) {
                if (tin) v = tin[(size_t)gr * DD + d];
                else     v = embed_word[(size_t)words[gr] * DD + d];
            }
            s[rr * 11 + d] = v;
        }
        __syncthreads();

        const float bias = *bptr;
        float acc[DD];
        #pragma unroll
        for (int d = 0; d < DD; ++d) acc[d] = bias;
        for (int i = 0; i < 23; ++i) {
            float row[DD];
            const float* sr = &s[(tid + i) * 11];
            #pragma unroll
            for (int c = 0; c < DD; ++c) row[c] = sr[c];
            #pragma unroll
            for (int d = 0; d < DD; ++d) {
                #pragma unroll
                for (int c = 0; c < DD; ++c)
                    acc[d] += row[c] * w[i * 23 + (c - d + 11)];
            }
        }
        const int l = l0 + tid;
        #pragma unroll
        for (int d = 0; d < DD; ++d)
            tout[(size_t)l * DD + d] = fmaxf(acc[d], 0.f);
    } else {
        // ================= GNN ROLE =================
        const int b = blockIdx.x - CONV_BLOCKS;     // 0..511
        const int wave = tid >> 6, lane = tid & 63;
        const int q = b & 3, rg = b >> 2;           // quarter / row group
        const int qbase = q * QCOLS;

        // ---- stage hs for this quarter: recompute from xs0 (+ prev parts)
        for (int j = 0; j < 4; ++j) {
            const int lc = j * 256 + tid;           // local col, lanes dense
            const int n = qbase + lc;
            float x[DD];
            #pragma unroll
            for (int d = 0; d < DD; ++d) x[d] = xs0[n * DD + d];
            if (p0) {
                #pragma unroll
                for (int qq = 0; qq < 4; ++qq)
                    #pragma unroll
                    for (int d = 0; d < DD; ++d)
                        x[d] += p0[((size_t)qq * N_ATOMS + n) * DD + d];
            }
            if (p1) {
                #pragma unroll
                for (int qq = 0; qq < 4; ++qq)
                    #pragma unroll
                    for (int d = 0; d < DD; ++d)
                        x[d] += p1[((size_t)qq * N_ATOMS + n) * DD + d];
            }
            #pragma unroll
            for (int d = 0; d < DD; ++d) {
                float v = bg[d];
                #pragma unroll
                for (int k = 0; k < DD; ++k) v += Wg[d * DD + k] * x[k];
                sh[d * QCOLS + lc] = fmaxf(v, 0.f);   // lanes dense: no conflict
            }
        }
        __syncthreads();

        const int r0 = rg * RPB + wave * RPW;
        const float4* A4 = (const float4*)(A + (size_t)r0 * N_ATOMS) + q * (QCOLS / 4);
        const float4* sh4 = (const float4*)sh;

        float acc[RPW][DD];
        #pragma unroll
        for (int r = 0; r < RPW; ++r)
            #pragma unroll
            for (int d = 0; d < DD; ++d) acc[r][d] = 0.f;

        // 1024 cols = 256 f4 / 64 lanes = 4 iterations; unroll 2 -> 16 A-loads
        // in flight per chunk, only A on the vmcnt queue.
        #pragma unroll 2
        for (int it = 0; it < 4; ++it) {
            const int cb = it * 64 + lane;
            float4 a[RPW];
            #pragma unroll
            for (int r = 0; r < RPW; ++r) a[r] = A4[r * (N_ATOMS / 4) + cb];
            #pragma unroll
            for (int d = 0; d < DD; ++d) {
                float4 h = sh4[d * 256 + cb];
                #pragma unroll
                for (int r = 0; r < RPW; ++r) {
                    acc[r][d] += a[r].x * h.x;
                    acc[r][d] += a[r].y * h.y;
                    acc[r][d] += a[r].z * h.z;
                    acc[r][d] += a[r].w * h.w;
                }
            }
        }

        // xor-butterfly: all lanes end with the row sums
        #pragma unroll
        for (int m = 32; m >= 1; m >>= 1) {
            #pragma unroll
            for (int r = 0; r < RPW; ++r)
                #pragma unroll
                for (int d = 0; d < DD; ++d)
                    acc[r][d] += __shfl_xor(acc[r][d], m, 64);
        }
        if (lane == 0) {
            #pragma unroll
            for (int r = 0; r < RPW; ++r)
                #pragma unroll
                for (int d = 0; d < DD; ++d)
                    part[((size_t)q * N_ATOMS + r0 + r) * DD + d] = acc[r][d];
        }
    }
}

// ---------------------------------------------------------------------------
// K3: comp_reduce — comp_part[16][10]; atom n's final x = xs0 + sum all parts
// ---------------------------------------------------------------------------
__global__ __launch_bounds__(256) void comp_reduce(
    const float* __restrict__ xs0, const float* __restrict__ p0,
    const float* __restrict__ p1, const float* __restrict__ p2,
    float* __restrict__ comp_part)
{
    const int tid = threadIdx.x, wave = tid >> 6, lane = tid & 63;
    const int n = blockIdx.x * 256 + tid;
    float x[DD];
    #pragma unroll
    for (int d = 0; d < DD; ++d) {
        float v = xs0[n * DD + d];
        #pragma unroll
        for (int qq = 0; qq < 4; ++qq) {
            v += p0[((size_t)qq * N_ATOMS + n) * DD + d];
            v += p1[((size_t)qq * N_ATOMS + n) * DD + d];
            v += p2[((size_t)qq * N_ATOMS + n) * DD + d];
        }
        x[d] = v;
    }
    #pragma unroll
    for (int m = 32; m >= 1; m >>= 1) {
        #pragma unroll
        for (int d = 0; d < DD; ++d) x[d] += __shfl_xor(x[d], m, 64);
    }
    __shared__ float s[4][DD];
    if (lane == 0) {
        #pragma unroll
        for (int d = 0; d < DD; ++d) s[wave][d] = x[d];
    }
    __syncthreads();
    if (tid < DD)
        comp_part[blockIdx.x * DD + tid] =
            s[0][tid] + s[1][tid] + s[2][tid] + s[3][tid];
}

// ---------------------------------------------------------------------------
// K4: attention pooling (comp derived in-block from comp_part; no extra launch)
// ---------------------------------------------------------------------------
__global__ __launch_bounds__(1024) void attention_pool(
    const float* __restrict__ xs_p, const float* __restrict__ comp_part,
    const float* __restrict__ Wa, const float* __restrict__ ba,
    float* __restrict__ att_part)
{
    __shared__ float shc[DD];
    __shared__ float s[16][DD];
    const int tid = threadIdx.x, wave = tid >> 6, lane = tid & 63;
    const int l = blockIdx.x * 1024 + tid;

    if (tid < DD) {
        float c = 0.f;
        #pragma unroll
        for (int p = 0; p < 16; ++p) c += comp_part[p * DD + tid];
        shc[tid] = c * (1.f / N_ATOMS);
    }
    __syncthreads();

    float h[DD];
    #pragma unroll
    for (int d = 0; d < DD; ++d) {
        float v = ba[d];
        #pragma unroll
        for (int k = 0; k < DD; ++k) v += Wa[d * DD + k] * shc[k];
        h[d] = fmaxf(v, 0.f);
    }

    float row[DD];
    #pragma unroll
    for (int d = 0; d < DD; ++d) row[d] = xs_p[(size_t)l * DD + d];

    float hp[DD], dotv = 0.f;
    #pragma unroll
    for (int d = 0; d < DD; ++d) {
        float v = ba[d];
        #pragma unroll
        for (int k = 0; k < DD; ++k) v += Wa[d * DD + k] * row[k];
        hp[d] = fmaxf(v, 0.f);
        dotv += h[d] * hp[d];
    }
    const float wgt = tanhf(dotv);

    float y[DD];
    #pragma unroll
    for (int d = 0; d < DD; ++d) y[d] = wgt * hp[d];
    #pragma unroll
    for (int m = 32; m >= 1; m >>= 1) {
        #pragma unroll
        for (int d = 0; d < DD; ++d) y[d] += __shfl_xor(y[d], m, 64);
    }
    if (lane == 0) {
        #pragma unroll
        for (int d = 0; d < DD; ++d) s[wave][d] = y[d];
    }
    __syncthreads();
    if (tid < DD) {
        float v = 0.f;
        #pragma unroll
        for (int wv = 0; wv < 16; ++wv) v += s[wv][tid];
        att_part[blockIdx.x * DD + tid] = v;
    }
}

// ---------------------------------------------------------------------------
// K5: final MLP (comp + protein derived in-block)
// ---------------------------------------------------------------------------
__global__ __launch_bounds__(64) void final_mlp(
    const float* __restrict__ comp_part, const float* __restrict__ att_part,
    const float* __restrict__ Wo, const float* __restrict__ bo,
    const float* __restrict__ Wi, const float* __restrict__ bi,
    float* __restrict__ out)
{
    const int t = threadIdx.x;
    float a[DD];
    #pragma unroll
    for (int d = 0; d < DD; ++d) a[d] = att_part[t * DD + d];
    #pragma unroll
    for (int m = 32; m >= 1; m >>= 1) {
        #pragma unroll
        for (int d = 0; d < DD; ++d) a[d] += __shfl_xor(a[d], m, 64);
    }
    __shared__ float cat[20];
    if (t < DD) {
        float c = 0.f;
        #pragma unroll
        for (int p = 0; p < 16; ++p) c += comp_part[p * DD + t];
        cat[t] = c * (1.f / N_ATOMS);
    }
    if (t == 0) {
        #pragma unroll
        for (int d = 0; d < DD; ++d) cat[DD + d] = a[d] * (1.f / L_WORDS);
    }
    __syncthreads();
    for (int j = 0; j < 3; ++j) {
        float v = 0.f;
        if (t < 20) {
            v = bo[j * 20 + t];
            for (int k = 0; k < 20; ++k) v += Wo[j * 400 + t * 20 + k] * cat[k];
        }
        __syncthreads();
        if (t < 20) cat[t] = fmaxf(v, 0.f);
        __syncthreads();
    }
    if (t < 2) {
        float v = bi[t];
        for (int k = 0; k < 20; ++k) v += Wi[t * 20 + k] * cat[k];
        out[t] = v;
    }
}

// ---------------------------------------------------------------------------
extern "C" void kernel_launch(void* const* d_in, const int* in_sizes, int n_in,
                              void* d_out, int out_size, void* d_ws, size_t ws_size,
                              hipStream_t stream)
{
    const int*   fp     = (const int*)d_in[0];
    const float* A      = (const float*)d_in[1];
    const int*   words  = (const int*)d_in[2];
    const float* emb_fp = (const float*)d_in[3];
    const float* emb_w  = (const float*)d_in[4];
    const float* Wg     = (const float*)d_in[5];   // [3][10][10]
    const float* bg     = (const float*)d_in[6];   // [3][10]
    const float* Wc     = (const float*)d_in[7];   // [3][529]
    const float* bc     = (const float*)d_in[8];   // [3]
    const float* Wa     = (const float*)d_in[9];   // [10][10]
    const float* ba     = (const float*)d_in[10];  // [10]
    const float* Wo     = (const float*)d_in[11];  // [3][20][20]
    const float* bo     = (const float*)d_in[12];  // [3][20]
    const float* Wi     = (const float*)d_in[13];  // [2][20]
    const float* bi     = (const float*)d_in[14];  // [2]
    float* out = (float*)d_out;
    float* ws  = (float*)d_ws;

    float* xs0   = ws;                       // 40960
    float* ta    = ws + 40960;               // 655360
    float* tb    = ws + 696320;              // 655360
    float* part0 = ws + 1351680;             // 163840
    float* part1 = ws + 1515520;             // 163840
    float* part2 = ws + 1679360;             // 163840
    float* comp_part = ws + 1843200;         // 160
    float* att_part  = ws + 1843456;         // 640

    const int fused_grid = CONV_BLOCKS + GNN_BLOCKS;   // 768 = 3 blocks/CU

    // All cross-layer ordering via kernel boundaries (no atomics/fences).
    gnn_embed<<<N_ATOMS / 256, 256, 0, stream>>>(fp, emb_fp, xs0);

    fused_layer<<<fused_grid, 256, 0, stream>>>(
        A, xs0, nullptr, nullptr, part0, Wg, bg,
        nullptr, words, emb_w, Wc, bc, ta);

    fused_layer<<<fused_grid, 256, 0, stream>>>(
        A, xs0, part0, nullptr, part1, Wg + 100, bg + 10,
        ta, nullptr, nullptr, Wc + 529, bc + 1, tb);

    fused_layer<<<fused_grid, 256, 0, stream>>>(
        A, xs0, part0, part1, part2, Wg + 200, bg + 20,
        tb, nullptr, nullptr, Wc + 1058, bc + 2, ta);

    comp_reduce<<<16, 256, 0, stream>>>(xs0, part0, part1, part2, comp_part);

    attention_pool<<<L_WORDS / 1024, 1024, 0, stream>>>(
        ta, comp_part, Wa, ba, att_part);

    final_mlp<<<1, 64, 0, stream>>>(comp_part, att_part, Wo, bo, Wi, bi, out);
}

// Round 9
// 204.345 us; speedup vs baseline: 4.4510x; 1.0318x over previous
//
#include <hip/hip_runtime.h>
#include <hip/hip_bf16.h>
#include <math.h>

#define N_ATOMS 4096
#define L_WORDS 65536
#define DD 10
#define HALO 11

#define CONV_BLOCKS 256
#define CONV_BLOCK 256
#define GNN_BLOCKS 512            // 128 row-groups x 4 column quarters
#define RPW 8                     // rows per wave
#define RPB 32                    // rows per block (4 waves)
#define QCOLS 1024                // columns per quarter

// ---------------------------------------------------------------------------
// K1: embedding gather -> xs0 only (hs is never materialized anywhere).
// ---------------------------------------------------------------------------
__global__ __launch_bounds__(256) void gnn_embed(
    const int* __restrict__ fp, const float* __restrict__ embed_fp,
    float* __restrict__ xs0)
{
    int n = blockIdx.x * blockDim.x + threadIdx.x;
    if (n >= N_ATOMS) return;
    const float* e = embed_fp + (size_t)fp[n] * DD;
    #pragma unroll
    for (int d = 0; d < DD; ++d) xs0[n * DD + d] = e[d];
}

// ---------------------------------------------------------------------------
// K2: fused_layer — role-split grid, NO atomics / NO fences.
//  blocks [0,256):   CNN layer (VALU-bound, hidden under GNN memory waits)
//  blocks [256,768): GNN partial A@hs over a 1024-column quarter.
// launch_bounds(256,3): VGPR<=170 so ALL 768 blocks are co-resident
// (3 blocks/CU, 12 waves/CU, 120KB LDS/CU) — round-8 ran 2 batches.
// Reduction: 3-step xor butterfly (8-lane groups) + LDS finish
// (240 swizzles/wave instead of 480, and a coalesced 320-float part write).
// ---------------------------------------------------------------------------
__global__ __launch_bounds__(256, 3) void fused_layer(
    const float* __restrict__ A,
    const float* __restrict__ xs0,
    const float* __restrict__ p0,        // part of layer 0 (null in L0)
    const float* __restrict__ p1,        // part of layer 1 (null in L0/L1)
    float* __restrict__ part,            // this layer's output [4][4096][10]
    const float* __restrict__ Wg, const float* __restrict__ bg,
    const float* __restrict__ tin, const int* __restrict__ words,
    const float* __restrict__ embed_word, const float* __restrict__ w,
    const float* __restrict__ bptr, float* __restrict__ tout)
{
    __shared__ float sh[DD * QCOLS];     // 40 KB exactly
    const int tid = threadIdx.x;

    if (blockIdx.x < CONV_BLOCKS) {
        // ================= CONV ROLE =================
        float* s = sh;                   // (256+22)*11 floats, stride 11
        const int l0 = blockIdx.x * CONV_BLOCK;
        for (int idx = tid; idx < (CONV_BLOCK + 2 * HALO) * DD; idx += CONV_BLOCK) {
            int rr = idx / DD, d = idx - rr * DD;
            int gr = l0 - HALO + rr;
            float v = 0.f;
            if (gr >= 0 && gr < L_WORDS) {
                if (tin) v = tin[(size_t)gr * DD + d];
                else     v = embed_word[(size_t)words[gr] * DD + d];
            }
            s[rr * 11 + d] = v;
        }
        __syncthreads();

        const float bias = *bptr;
        float acc[DD];
        #pragma unroll
        for (int d = 0; d < DD; ++d) acc[d] = bias;
        for (int i = 0; i < 23; ++i) {
            float row[DD];
            const float* sr = &s[(tid + i) * 11];
            #pragma unroll
            for (int c = 0; c < DD; ++c) row[c] = sr[c];
            #pragma unroll
            for (int d = 0; d < DD; ++d) {
                #pragma unroll
                for (int c = 0; c < DD; ++c)
                    acc[d] += row[c] * w[i * 23 + (c - d + 11)];
            }
        }
        const int l = l0 + tid;
        #pragma unroll
        for (int d = 0; d < DD; ++d)
            tout[(size_t)l * DD + d] = fmaxf(acc[d], 0.f);
    } else {
        // ================= GNN ROLE =================
        const int b = blockIdx.x - CONV_BLOCKS;     // 0..511
        const int wave = tid >> 6, lane = tid & 63;
        const int q = b & 3, rg = b >> 2;           // quarter / row group
        const int qbase = q * QCOLS;

        // ---- stage hs for this quarter: recompute from xs0 (+ prev parts)
        for (int j = 0; j < 4; ++j) {
            const int lc = j * 256 + tid;           // local col, lanes dense
            const int n = qbase + lc;
            float x[DD];
            #pragma unroll
            for (int d = 0; d < DD; ++d) x[d] = xs0[n * DD + d];
            if (p0) {
                #pragma unroll
                for (int qq = 0; qq < 4; ++qq)
                    #pragma unroll
                    for (int d = 0; d < DD; ++d)
                        x[d] += p0[((size_t)qq * N_ATOMS + n) * DD + d];
            }
            if (p1) {
                #pragma unroll
                for (int qq = 0; qq < 4; ++qq)
                    #pragma unroll
                    for (int d = 0; d < DD; ++d)
                        x[d] += p1[((size_t)qq * N_ATOMS + n) * DD + d];
            }
            #pragma unroll
            for (int d = 0; d < DD; ++d) {
                float v = bg[d];
                #pragma unroll
                for (int k = 0; k < DD; ++k) v += Wg[d * DD + k] * x[k];
                sh[d * QCOLS + lc] = fmaxf(v, 0.f);   // lanes dense: no conflict
            }
        }
        __syncthreads();

        const int r0 = rg * RPB + wave * RPW;
        const float4* A4 = (const float4*)(A + (size_t)r0 * N_ATOMS) + q * (QCOLS / 4);
        const float4* sh4 = (const float4*)sh;

        float acc[RPW][DD];
        #pragma unroll
        for (int r = 0; r < RPW; ++r)
            #pragma unroll
            for (int d = 0; d < DD; ++d) acc[r][d] = 0.f;

        // 4 iterations, NOT unrolled: 8 A-loads in flight/wave (96/CU at 12
        // waves/CU) keeps VGPRs ~140 < 170 cap while saturating the queue.
        #pragma unroll 1
        for (int it = 0; it < 4; ++it) {
            const int cb = it * 64 + lane;
            float4 a[RPW];
            #pragma unroll
            for (int r = 0; r < RPW; ++r) a[r] = A4[r * (N_ATOMS / 4) + cb];
            #pragma unroll
            for (int d = 0; d < DD; ++d) {
                float4 h = sh4[d * 256 + cb];
                #pragma unroll
                for (int r = 0; r < RPW; ++r) {
                    acc[r][d] += a[r].x * h.x;
                    acc[r][d] += a[r].y * h.y;
                    acc[r][d] += a[r].z * h.z;
                    acc[r][d] += a[r].w * h.w;
                }
            }
        }

        // ---- reduction: 3 xor steps within 8-lane groups ----
        #pragma unroll
        for (int m = 1; m <= 4; m <<= 1) {
            #pragma unroll
            for (int r = 0; r < RPW; ++r)
                #pragma unroll
                for (int d = 0; d < DD; ++d)
                    acc[r][d] += __shfl_xor(acc[r][d], m, 64);
        }
        __syncthreads();   // hs in LDS no longer needed by any wave

        // group leaders (lane%8==0) stash partials: [wave][group][80]
        if ((lane & 7) == 0) {
            const int g = lane >> 3;
            float* dst = &sh[(wave * 8 + g) * 80];
            #pragma unroll
            for (int r = 0; r < RPW; ++r)
                #pragma unroll
                for (int d = 0; d < DD; ++d) dst[r * DD + d] = acc[r][d];
        }
        __syncthreads();

        // block finish: 320 outputs (32 rows x 10), coalesced part write
        float* pdst = part + ((size_t)q * N_ATOMS + rg * RPB) * DD;
        for (int o = tid; o < RPB * DD; o += 256) {
            const int w8 = o / 80;           // wave
            const int k = o - w8 * 80;       // r*10+d
            float v = 0.f;
            #pragma unroll
            for (int g = 0; g < 8; ++g) v += sh[(w8 * 8 + g) * 80 + k];
            pdst[o] = v;
        }
    }
}

// ---------------------------------------------------------------------------
// K3: comp_reduce — comp_part[16][10]; atom n's final x = xs0 + sum all parts
// ---------------------------------------------------------------------------
__global__ __launch_bounds__(256) void comp_reduce(
    const float* __restrict__ xs0, const float* __restrict__ p0,
    const float* __restrict__ p1, const float* __restrict__ p2,
    float* __restrict__ comp_part)
{
    const int tid = threadIdx.x, wave = tid >> 6, lane = tid & 63;
    const int n = blockIdx.x * 256 + tid;
    float x[DD];
    #pragma unroll
    for (int d = 0; d < DD; ++d) {
        float v = xs0[n * DD + d];
        #pragma unroll
        for (int qq = 0; qq < 4; ++qq) {
            v += p0[((size_t)qq * N_ATOMS + n) * DD + d];
            v += p1[((size_t)qq * N_ATOMS + n) * DD + d];
            v += p2[((size_t)qq * N_ATOMS + n) * DD + d];
        }
        x[d] = v;
    }
    #pragma unroll
    for (int m = 32; m >= 1; m >>= 1) {
        #pragma unroll
        for (int d = 0; d < DD; ++d) x[d] += __shfl_xor(x[d], m, 64);
    }
    __shared__ float s[4][DD];
    if (lane == 0) {
        #pragma unroll
        for (int d = 0; d < DD; ++d) s[wave][d] = x[d];
    }
    __syncthreads();
    if (tid < DD)
        comp_part[blockIdx.x * DD + tid] =
            s[0][tid] + s[1][tid] + s[2][tid] + s[3][tid];
}

// ---------------------------------------------------------------------------
// K4: attention pooling (comp derived in-block from comp_part)
// ---------------------------------------------------------------------------
__global__ __launch_bounds__(1024) void attention_pool(
    const float* __restrict__ xs_p, const float* __restrict__ comp_part,
    const float* __restrict__ Wa, const float* __restrict__ ba,
    float* __restrict__ att_part)
{
    __shared__ float shc[DD];
    __shared__ float s[16][DD];
    const int tid = threadIdx.x, wave = tid >> 6, lane = tid & 63;
    const int l = blockIdx.x * 1024 + tid;

    if (tid < DD) {
        float c = 0.f;
        #pragma unroll
        for (int p = 0; p < 16; ++p) c += comp_part[p * DD + tid];
        shc[tid] = c * (1.f / N_ATOMS);
    }
    __syncthreads();

    float h[DD];
    #pragma unroll
    for (int d = 0; d < DD; ++d) {
        float v = ba[d];
        #pragma unroll
        for (int k = 0; k < DD; ++k) v += Wa[d * DD + k] * shc[k];
        h[d] = fmaxf(v, 0.f);
    }

    float row[DD];
    #pragma unroll
    for (int d = 0; d < DD; ++d) row[d] = xs_p[(size_t)l * DD + d];

    float hp[DD], dotv = 0.f;
    #pragma unroll
    for (int d = 0; d < DD; ++d) {
        float v = ba[d];
        #pragma unroll
        for (int k = 0; k < DD; ++k) v += Wa[d * DD + k] * row[k];
        hp[d] = fmaxf(v, 0.f);
        dotv += h[d] * hp[d];
    }
    const float wgt = tanhf(dotv);

    float y[DD];
    #pragma unroll
    for (int d = 0; d < DD; ++d) y[d] = wgt * hp[d];
    #pragma unroll
    for (int m = 32; m >= 1; m >>= 1) {
        #pragma unroll
        for (int d = 0; d < DD; ++d) y[d] += __shfl_xor(y[d], m, 64);
    }
    if (lane == 0) {
        #pragma unroll
        for (int d = 0; d < DD; ++d) s[wave][d] = y[d];
    }
    __syncthreads();
    if (tid < DD) {
        float v = 0.f;
        #pragma unroll
        for (int wv = 0; wv < 16; ++wv) v += s[wv][tid];
        att_part[blockIdx.x * DD + tid] = v;
    }
}

// ---------------------------------------------------------------------------
// K5: final MLP (comp + protein derived in-block)
// ---------------------------------------------------------------------------
__global__ __launch_bounds__(64) void final_mlp(
    const float* __restrict__ comp_part, const float* __restrict__ att_part,
    const float* __restrict__ Wo, const float* __restrict__ bo,
    const float* __restrict__ Wi, const float* __restrict__ bi,
    float* __restrict__ out)
{
    const int t = threadIdx.x;
    float a[DD];
    #pragma unroll
    for (int d = 0; d < DD; ++d) a[d] = att_part[t * DD + d];
    #pragma unroll
    for (int m = 32; m >= 1; m >>= 1) {
        #pragma unroll
        for (int d = 0; d < DD; ++d) a[d] += __shfl_xor(a[d], m, 64);
    }
    __shared__ float cat[20];
    if (t < DD) {
        float c = 0.f;
        #pragma unroll
        for (int p = 0; p < 16; ++p) c += comp_part[p * DD + t];
        cat[t] = c * (1.f / N_ATOMS);
    }
    if (t == 0) {
        #pragma unroll
        for (int d = 0; d < DD; ++d) cat[DD + d] = a[d] * (1.f / L_WORDS);
    }
    __syncthreads();
    for (int j = 0; j < 3; ++j) {
        float v = 0.f;
        if (t < 20) {
            v = bo[j * 20 + t];
            for (int k = 0; k < 20; ++k) v += Wo[j * 400 + t * 20 + k] * cat[k];
        }
        __syncthreads();
        if (t < 20) cat[t] = fmaxf(v, 0.f);
        __syncthreads();
    }
    if (t < 2) {
        float v = bi[t];
        for (int k = 0; k < 20; ++k) v += Wi[t * 20 + k] * cat[k];
        out[t] = v;
    }
}

// ---------------------------------------------------------------------------
extern "C" void kernel_launch(void* const* d_in, const int* in_sizes, int n_in,
                              void* d_out, int out_size, void* d_ws, size_t ws_size,
                              hipStream_t stream)
{
    const int*   fp     = (const int*)d_in[0];
    const float* A      = (const float*)d_in[1];
    const int*   words  = (const int*)d_in[2];
    const float* emb_fp = (const float*)d_in[3];
    const float* emb_w  = (const float*)d_in[4];
    const float* Wg     = (const float*)d_in[5];   // [3][10][10]
    const float* bg     = (const float*)d_in[6];   // [3][10]
    const float* Wc     = (const float*)d_in[7];   // [3][529]
    const float* bc     = (const float*)d_in[8];   // [3]
    const float* Wa     = (const float*)d_in[9];   // [10][10]
    const float* ba     = (const float*)d_in[10];  // [10]
    const float* Wo     = (const float*)d_in[11];  // [3][20][20]
    const float* bo     = (const float*)d_in[12];  // [3][20]
    const float* Wi     = (const float*)d_in[13];  // [2][20]
    const float* bi     = (const float*)d_in[14];  // [2]
    float* out = (float*)d_out;
    float* ws  = (float*)d_ws;

    float* xs0   = ws;                       // 40960
    float* ta    = ws + 40960;               // 655360
    float* tb    = ws + 696320;              // 655360
    float* part0 = ws + 1351680;             // 163840
    float* part1 = ws + 1515520;             // 163840
    float* part2 = ws + 1679360;             // 163840
    float* comp_part = ws + 1843200;         // 160
    float* att_part  = ws + 1843456;         // 640

    const int fused_grid = CONV_BLOCKS + GNN_BLOCKS;   // 768 = 3 blocks/CU

    // All cross-layer ordering via kernel boundaries (no atomics/fences).
    gnn_embed<<<N_ATOMS / 256, 256, 0, stream>>>(fp, emb_fp, xs0);

    fused_layer<<<fused_grid, 256, 0, stream>>>(
        A, xs0, nullptr, nullptr, part0, Wg, bg,
        nullptr, words, emb_w, Wc, bc, ta);

    fused_layer<<<fused_grid, 256, 0, stream>>>(
        A, xs0, part0, nullptr, part1, Wg + 100, bg + 10,
        ta, nullptr, nullptr, Wc + 529, bc + 1, tb);

    fused_layer<<<fused_grid, 256, 0, stream>>>(
        A, xs0, part0, part1, part2, Wg + 200, bg + 20,
        tb, nullptr, nullptr, Wc + 1058, bc + 2, ta);

    comp_reduce<<<16, 256, 0, stream>>>(xs0, part0, part1, part2, comp_part);

    attention_pool<<<L_WORDS / 1024, 1024, 0, stream>>>(
        ta, comp_part, Wa, ba, att_part);

    final_mlp<<<1, 64, 0, stream>>>(comp_part, att_part, Wo, bo, Wi, bi, out);
}